// Round 15
// baseline (2030.464 us; speedup 1.0000x reference)
//
#include <hip/hip_runtime.h>

#define TT 4000   // timesteps
#define HH 64     // hidden
#define NB 256    // batch
#define EE 128    // fc out

typedef __attribute__((ext_vector_type(2))) _Float16 h2;
typedef __attribute__((ext_vector_type(8))) _Float16 h8;

__device__ __forceinline__ float ftanh(float x) {
    return fmaf(2.f, __builtin_amdgcn_rcpf(1.f + __expf(-2.f * x)), -1.f);
}

#if __has_builtin(__builtin_amdgcn_fdot2)
#define FDOT2(a, b, c) __builtin_amdgcn_fdot2((a), (b), (c), false)
#else
#define FDOT2(a, b, c) fmaf((float)(a).x, (float)(b).x, fmaf((float)(a).y, (float)(b).y, (c)))
#endif

// h2 sub-extract from h8 register (sub-register addressing, no memory).
#define H2V(V, i) (__builtin_shufflevector((V), (V), 2 * (i), 2 * (i) + 1))

// DPP helpers (VALU pipe, no LDS). ctrl must be an ICE -> template param.
template <int CTRL>
__device__ __forceinline__ float dpp_mov(float v) {
    return __int_as_float(__builtin_amdgcn_update_dpp(
        0, __float_as_int(v), CTRL, 0xF, 0xF, true));
}
#define DPP_XOR1 0xB1   // quad_perm [1,0,3,2]  (flip s)      [HW-verified R8/R9/R14]
#define DPP_XOR2 0x4E   // quad_perm [2,3,0,1]  (flip u)      [HW-verified]
#define DPP_FB   0x44   // quad_perm [0,1,0,1]  (broadcast u=0 per s)
#define DPP_OB   0xEE   // quad_perm [2,3,2,3]  (broadcast u=1 per s)
#define DPP_SHR4 0x114  // row_shr:4  p=0 quad -> p=1 quad    [HW-verified R14]

#define CVT2(d0, d1, s) h2 d0 = h2{(_Float16)(s).x, (_Float16)(s).y}, \
                           d1 = h2{(_Float16)(s).z, (_Float16)(s).w};

// ---- One LSTM step. PAR/L0OK/L1OK are compile-time; interior steps have no
// selects and constant LDS offsets (2-step unroll). Split accumulator chains
// (acc0: 2x8, acc1: 4x8 fdot2) for dependency-latency ILP in the tail.
#define STEP(PAR, L0OK, L1OK, XT) do {                                        \
    const h8* hb_ = (const h8*)hbuf[PAR];                                     \
    h8 Ha = hb_[4*ss+0], Hc = hb_[4*ss+1], He = hb_[4*ss+2], Hg = hb_[4*ss+3];\
    h8 Ga = hb_[8+4*ss+0], Gc = hb_[8+4*ss+1];                                \
    h8 Ge = hb_[8+4*ss+2], Gg = hb_[8+4*ss+3];                                \
    float a0a = ss ? 0.f : fmaf((XT), wx, bb0);                               \
    float a0b = 0.f;                                                          \
    float a1a = ss ? 0.f : bb1;                                               \
    float a1b = 0.f, a1c = 0.f, a1d = 0.f;                                    \
    a0a = FDOT2(A0,  H2V(Ha,0), a0a); a0a = FDOT2(A1,  H2V(Ha,1), a0a);       \
    a0a = FDOT2(A2,  H2V(Ha,2), a0a); a0a = FDOT2(A3,  H2V(Ha,3), a0a);       \
    a0a = FDOT2(A4,  H2V(Hc,0), a0a); a0a = FDOT2(A5,  H2V(Hc,1), a0a);       \
    a0a = FDOT2(A6,  H2V(Hc,2), a0a); a0a = FDOT2(A7,  H2V(Hc,3), a0a);       \
    a0b = FDOT2(A8,  H2V(He,0), a0b); a0b = FDOT2(A9,  H2V(He,1), a0b);       \
    a0b = FDOT2(A10, H2V(He,2), a0b); a0b = FDOT2(A11, H2V(He,3), a0b);       \
    a0b = FDOT2(A12, H2V(Hg,0), a0b); a0b = FDOT2(A13, H2V(Hg,1), a0b);       \
    a0b = FDOT2(A14, H2V(Hg,2), a0b); a0b = FDOT2(A15, H2V(Hg,3), a0b);       \
    a1a = FDOT2(B0,  H2V(Ha,0), a1a); a1a = FDOT2(B1,  H2V(Ha,1), a1a);       \
    a1a = FDOT2(B2,  H2V(Ha,2), a1a); a1a = FDOT2(B3,  H2V(Ha,3), a1a);       \
    a1a = FDOT2(B4,  H2V(Hc,0), a1a); a1a = FDOT2(B5,  H2V(Hc,1), a1a);       \
    a1a = FDOT2(B6,  H2V(Hc,2), a1a); a1a = FDOT2(B7,  H2V(Hc,3), a1a);       \
    a1b = FDOT2(B8,  H2V(He,0), a1b); a1b = FDOT2(B9,  H2V(He,1), a1b);       \
    a1b = FDOT2(B10, H2V(He,2), a1b); a1b = FDOT2(B11, H2V(He,3), a1b);       \
    a1b = FDOT2(B12, H2V(Hg,0), a1b); a1b = FDOT2(B13, H2V(Hg,1), a1b);       \
    a1b = FDOT2(B14, H2V(Hg,2), a1b); a1b = FDOT2(B15, H2V(Hg,3), a1b);       \
    a1c = FDOT2(C0,  H2V(Ga,0), a1c); a1c = FDOT2(C1,  H2V(Ga,1), a1c);       \
    a1c = FDOT2(C2,  H2V(Ga,2), a1c); a1c = FDOT2(C3,  H2V(Ga,3), a1c);       \
    a1c = FDOT2(C4,  H2V(Gc,0), a1c); a1c = FDOT2(C5,  H2V(Gc,1), a1c);       \
    a1c = FDOT2(C6,  H2V(Gc,2), a1c); a1c = FDOT2(C7,  H2V(Gc,3), a1c);       \
    a1d = FDOT2(C8,  H2V(Ge,0), a1d); a1d = FDOT2(C9,  H2V(Ge,1), a1d);       \
    a1d = FDOT2(C10, H2V(Ge,2), a1d); a1d = FDOT2(C11, H2V(Ge,3), a1d);       \
    a1d = FDOT2(C12, H2V(Gg,0), a1d); a1d = FDOT2(C13, H2V(Gg,1), a1d);       \
    a1d = FDOT2(C14, H2V(Gg,2), a1d); a1d = FDOT2(C15, H2V(Gg,3), a1d);       \
    float acc0 = a0a + a0b;                                                   \
    float acc1 = (a1a + a1b) + (a1c + a1d);                                   \
    acc0 += dpp_mov<DPP_XOR1>(acc0);                                          \
    acc1 += dpp_mov<DPP_XOR1>(acc1);                                          \
    float z  = ss ? acc1 : acc0;                                              \
    float ez = __expf(kk * z);                                                \
    float val = fmaf(mm, __builtin_amdgcn_rcpf(1.f + ez), aa);                \
    float igq = val * dpp_mov<DPP_XOR2>(val);                                 \
    float ig  = dpp_mov<DPP_SHR4>(igq);                                       \
    float fb  = dpp_mov<DPP_FB>(val);                                         \
    float ob  = dpp_mov<DPP_OB>(val);                                         \
    float cn = fmaf(fb, cc, ig);                                              \
    float hn = ob * ftanh(cn);                                                \
    if ((L0OK) && (L1OK)) {                                                   \
        cc = cn;                                                              \
        if (wlane) hbuf[(PAR) ^ 1][hoff] = (_Float16)hn;                      \
    } else {                                                                  \
        bool ok = ss ? (bool)(L1OK) : (bool)(L0OK);                           \
        cc = ok ? cn : cc;                                                    \
        if (wlane && ok) hbuf[(PAR) ^ 1][hoff] = (_Float16)hn;                \
    }                                                                         \
    __syncthreads();                                                          \
} while (0)

// One block (512 thr) per batch element.
// lane = 16*rowgrp + 8*nn + 4*p + 2*u + s ; gate = p + 2u
// (p=0 quad: i,i,g,g ; p=1 quad: f,f,o,o), s = k-half (32 k) AND layer.
//
// R14 post-mortem: step=1180 cyc, VALU busy 690/SIMD vs ~200 hand-counted —
// the excess is per-iteration LDS address recomputation (parity-dependent
// bases), boundary selects, and 16/32-deep serial fdot2 chains. R15: 2-step
// unroll (compile-time parity -> constant ds offsets), peel t=0/1/TT
// (interior select-free), split accumulator chains for ILP. Math identical.
// SQ_LDS_BANK_CONFLICT ~1.6e7 is the benign 2-addr b128 divergence
// (~16 cyc/step/CU), not swizzles — stop chasing it.
__global__ __launch_bounds__(512, 2)
void lstm2_fc_kernel(const float* __restrict__ x,      // [B, T, 1]
                     const float* __restrict__ W_ih0,  // [256, 1]
                     const float* __restrict__ W_hh0,  // [256, 64]
                     const float* __restrict__ b_ih0,  // [256]
                     const float* __restrict__ b_hh0,  // [256]
                     const float* __restrict__ W_ih1,  // [256, 64]
                     const float* __restrict__ W_hh1,  // [256, 64]
                     const float* __restrict__ b_ih1,  // [256]
                     const float* __restrict__ b_hh1,  // [256]
                     const float* __restrict__ W_fc,   // [128, 64]
                     const float* __restrict__ b_fc,   // [128]
                     float* __restrict__ out)          // [B, 128]
{
    const int b    = blockIdx.x;
    const int tid  = threadIdx.x;     // 0..511
    const int w    = tid >> 6;        // wave 0..7
    const int lane = tid & 63;
    const int ss   = lane & 1;        // k-half AND layer assignment
    const int uu   = (lane >> 1) & 1;
    const int pp   = (lane >> 2) & 1;
    const int nn   = (lane >> 3) & 1;
    const int n    = w * 8 + (lane >> 4) * 2 + nn;   // h-index 0..63
    const int gidx = pp + 2 * uu;                    // 0:i 1:f 2:g 3:o

    __shared__ float x_s[TT];                          // 16 KB
    __shared__ __align__(16) _Float16 hbuf[2][2 * HH]; // [parity][h0|h1], fp16

    for (int t = tid; t < TT; t += 512) x_s[t] = x[(size_t)b * TT + t];
    if (tid < 4 * HH) ((_Float16*)hbuf)[tid] = (_Float16)0.f;

    const int row = gidx * HH + n;   // gate row in [0,256)
    // --- Named-scalar weight load: 3 thirty-two-wide slices -> 48 h2 ---
    const float4* p0 = (const float4*)(W_hh0 + row * HH + ss * 32);
    const float4* p1 = (const float4*)(W_ih1 + row * HH + ss * 32);
    const float4* p2 = (const float4*)(W_hh1 + row * HH + ss * 32);
    float4 a0 = p0[0], a1 = p0[1], a2 = p0[2], a3 = p0[3];
    float4 a4 = p0[4], a5 = p0[5], a6 = p0[6], a7 = p0[7];
    float4 e0 = p1[0], e1 = p1[1], e2 = p1[2], e3 = p1[3];
    float4 e4 = p1[4], e5 = p1[5], e6 = p1[6], e7 = p1[7];
    float4 d0 = p2[0], d1 = p2[1], d2 = p2[2], d3 = p2[3];
    float4 d4 = p2[4], d5 = p2[5], d6 = p2[6], d7 = p2[7];
    CVT2(A0,  A1,  a0) CVT2(A2,  A3,  a1) CVT2(A4,  A5,  a2) CVT2(A6,  A7,  a3)
    CVT2(A8,  A9,  a4) CVT2(A10, A11, a5) CVT2(A12, A13, a6) CVT2(A14, A15, a7)
    CVT2(B0,  B1,  e0) CVT2(B2,  B3,  e1) CVT2(B4,  B5,  e2) CVT2(B6,  B7,  e3)
    CVT2(B8,  B9,  e4) CVT2(B10, B11, e5) CVT2(B12, B13, e6) CVT2(B14, B15, e7)
    CVT2(C0,  C1,  d0) CVT2(C2,  C3,  d1) CVT2(C4,  C5,  d2) CVT2(C6,  C7,  d3)
    CVT2(C8,  C9,  d4) CVT2(C10, C11, d5) CVT2(C12, C13, d6) CVT2(C14, C15, d7)

    float wx  = W_ih0[row];
    float bb0 = b_ih0[row] + b_hh0[row];
    float bb1 = b_ih1[row] + b_hh1[row];

    // Remat fences (R7/R9/R14-proven).
    asm volatile("" : "+v"(A0), "+v"(A1), "+v"(A2),  "+v"(A3),
                      "+v"(A4), "+v"(A5), "+v"(A6),  "+v"(A7),
                      "+v"(A8), "+v"(A9), "+v"(A10), "+v"(A11),
                      "+v"(A12),"+v"(A13),"+v"(A14), "+v"(A15),
                      "+v"(B0), "+v"(B1), "+v"(B2),  "+v"(B3),
                      "+v"(B4), "+v"(B5), "+v"(B6),  "+v"(B7));
    asm volatile("" : "+v"(B8), "+v"(B9), "+v"(B10), "+v"(B11),
                      "+v"(B12),"+v"(B13),"+v"(B14), "+v"(B15),
                      "+v"(C0), "+v"(C1), "+v"(C2),  "+v"(C3),
                      "+v"(C4), "+v"(C5), "+v"(C6),  "+v"(C7),
                      "+v"(C8), "+v"(C9), "+v"(C10), "+v"(C11),
                      "+v"(C12),"+v"(C13),"+v"(C14), "+v"(C15),
                      "+v"(wx), "+v"(bb0),"+v"(bb1));

    // act(z) = mm * rcp(1 + exp(kk*z)) + aa ; tanh only for gate g (gidx==2).
    const bool isg = (gidx == 2);
    const float kk = isg ? -2.f : -1.f;
    const float mm = isg ?  2.f :  1.f;
    const float aa = isg ? -1.f :  0.f;

    const bool wlane = (pp == 1) && (uu == 0);   // h writers (f lanes)
    const int  hoff  = ss * HH + n;              // s=0 -> h0[n], s=1 -> h1[n]
    float cc = 0.f;                              // valid in p=1 lanes

    __syncthreads();

    // t=0 (L1 off), t=1, then interior pairs t=2..3999, then t=4000 (L0 off).
    STEP(0, 1, 0, x_s[0]);
    STEP(1, 1, 1, x_s[1]);
    const float* xp = x_s + 2;
    for (int tp = 0; tp < (TT - 2) / 2; ++tp) {
        STEP(0, 1, 1, xp[0]);
        STEP(1, 1, 1, xp[1]);
        xp += 2;
    }
    STEP(0, 0, 1, 0.f);

    // FC on final h1 = h1(TT-1), in hbuf[1][64..128).
    if (tid < EE) {
        const _Float16* h1f = &hbuf[1][HH];
        float acc = b_fc[tid];
        const float4* wf = (const float4*)(W_fc + tid * HH);
        #pragma unroll
        for (int k = 0; k < HH / 4; ++k) {
            float4 v = wf[k];
            acc = fmaf(v.x, (float)h1f[4*k+0], acc);
            acc = fmaf(v.y, (float)h1f[4*k+1], acc);
            acc = fmaf(v.z, (float)h1f[4*k+2], acc);
            acc = fmaf(v.w, (float)h1f[4*k+3], acc);
        }
        out[(size_t)b * EE + tid] = acc;
    }
}

extern "C" void kernel_launch(void* const* d_in, const int* in_sizes, int n_in,
                              void* d_out, int out_size, void* d_ws, size_t ws_size,
                              hipStream_t stream) {
    const float* x     = (const float*)d_in[0];
    const float* W_ih0 = (const float*)d_in[1];
    const float* W_hh0 = (const float*)d_in[2];
    const float* b_ih0 = (const float*)d_in[3];
    const float* b_hh0 = (const float*)d_in[4];
    const float* W_ih1 = (const float*)d_in[5];
    const float* W_hh1 = (const float*)d_in[6];
    const float* b_ih1 = (const float*)d_in[7];
    const float* b_hh1 = (const float*)d_in[8];
    const float* W_fc  = (const float*)d_in[9];
    const float* b_fc  = (const float*)d_in[10];
    float* out = (float*)d_out;

    lstm2_fc_kernel<<<dim3(NB), dim3(512), 0, stream>>>(
        x, W_ih0, W_hh0, b_ih0, b_hh0, W_ih1, W_hh1, b_ih1, b_hh1, W_fc, b_fc, out);
}